// Round 2
// baseline (417.705 us; speedup 1.0000x reference)
//
#include <hip/hip_runtime.h>
#include <cstdint>

// GRU recurrent autoencoder, MI355X persistent-MFMA implementation, round 9.
// B=2048, T=128, X=38, H=128, 3H=384. fp32 I/O, fp16 MFMA operands,
// fp32 accumulation + fp32 recurrent state (in registers).
//
// Round 9 = round-8 occupancy goal (2 WGs/CU) made safe + fitting:
//  * r8 failed replay-correctness (race class around raw lgkmcnt-barrier +
//    in-flight globals under spill pressure) and spilled (weights ~80 VGPR
//    don't shrink with BT; 145+ live > 128 cap -> 636us). Fixes:
//  * __syncthreads() everywhere (full vmcnt+lgkm drain; no custom barrier).
//  * x staged ONCE to LDS fp16 [T][BT][48] (48KB, unioned with w2lds - x is
//    dead before the decoder fold). Encoder loop has ZERO global ops -> the
//    per-step vmcnt(0) drain costs nothing. Decoder: 1 out-store issued
//    ~400cy before the barrier -> ack hidden.
//  * Register diet to genuinely fit 128 @ __launch_bounds__(512,4):
//    encoder ~113 live (72 weights + 16 acc + 8 xa + hc 4 + misc), decoder
//    ~120 (80 weights + 20 acc + hc 4 + misc). ha read per-c, consumed
//    immediately.
//  * Kept from r8 (verified pre-timing): BT=4 (batch=quad, C reg 0 only ->
//    1 activation+write/lane/step), merged r/z gi+gh accumulators, HS=160
//    (2-way LDS, free), decoder algebra (r/z folded dWhh+dWih*linW, n-gate
//    W2 separate, projection overlapped, t=0 pre-step).
//  * xa1: only quad 0 loads k=32..39 (38,39 zero-padded); quads 1-3 reuse
//    finite xa0 against all-zero weights (never 0 x Inf/NaN).

#define T_SEQ 128
#define X_DIM 38
#define H_DIM 128
#define B_TOT 2048
#define BT    4
#define HS    160   // h row stride in halfs; 80 dw == 16 mod 32 -> 2-way (free)
#define XK    48    // x row stride in halfs (k padded 38->48); 2-way banks

#define HB_BYTES   (2 * BT * HS * 2)            // 2560
#define XW_BYTES   (T_SEQ * BT * XK * 2)        // 49152 (>= 32768 w2lds)
#define SMEM_BYTES (HB_BYTES + XW_BYTES)        // 51712

typedef _Float16 half8 __attribute__((ext_vector_type(8)));
typedef float    f32x4 __attribute__((ext_vector_type(4)));

__device__ __forceinline__ float fast_sigmoid(float x) {
    return __builtin_amdgcn_rcpf(1.0f + __expf(-x));
}
__device__ __forceinline__ float fast_tanh(float x) {
    return 1.0f - 2.0f * __builtin_amdgcn_rcpf(1.0f + __expf(2.0f * x));
}

__global__ __launch_bounds__(512, 4)
void rae_gru_kernel(const float* __restrict__ x,
                    const float* __restrict__ eWih, const float* __restrict__ eWhh,
                    const float* __restrict__ ebih, const float* __restrict__ ebhh,
                    const float* __restrict__ dWih, const float* __restrict__ dWhh,
                    const float* __restrict__ dbih, const float* __restrict__ dbhh,
                    const float* __restrict__ linW, const float* __restrict__ linb,
                    float* __restrict__ out)
{
    __shared__ __align__(16) unsigned char smem[SMEM_BYTES];
    _Float16* const hbuf  = (_Float16*)smem;                    // [2][BT][HS]
    _Float16* const xlds  = (_Float16*)(smem + HB_BYTES);       // [T][BT][XK]
    _Float16* const w2lds = (_Float16*)(smem + HB_BYTES);       // [128][128], decoder prep (x dead)

    const int tid  = threadIdx.x;
    const int wv   = tid >> 6;        // 0..7
    const int ln   = tid & 63;
    const int quad = ln >> 4;         // A/B: k-group; C: row-group (= batch)
    const int mrow = ln & 15;         // A: m-row / B,C: col-in-tile
    const int b0   = blockIdx.x * BT;
    const int arow = mrow >> 2;       // batch row this A-lane reads (b at m=4b)
    const int j    = wv * 16 + mrow;  // this lane's gate column (8 waves x 16)
    const int jc0  = j, jc1 = H_DIM + j, jc2 = 2 * H_DIM + j;

    {   // zero all of LDS (h0 = 0, x pad columns = 0)
        uint32_t* p = (uint32_t*)smem;
        #pragma unroll 1
        for (int i = tid; i < SMEM_BYTES / 4; i += 512) p[i] = 0u;
    }
    __syncthreads();

    // ---- stage x -> LDS fp16, layout [t][row][k(48)] ----
    // 512 threads == 4 rows x 128 t: thread -> (row = tid>>7, t = tid&127).
    {
        const int r = tid >> 7, t = tid & 127;
        const float* src = x + ((size_t)(b0 + r) * T_SEQ + t) * X_DIM;
        _Float16* dst = xlds + t * (BT * XK) + r * XK;
        float v[38];
        #pragma unroll
        for (int u = 0; u < 19; ++u) {
            float2 w = *(const float2*)(src + 2 * u);
            v[2 * u] = w.x; v[2 * u + 1] = w.y;
        }
        #pragma unroll
        for (int c = 0; c < 4; ++c) {
            half8 hv;
            #pragma unroll
            for (int e = 0; e < 8; ++e) hv[e] = (_Float16)v[c * 8 + e];
            *(half8*)(dst + c * 8) = hv;
        }
        {
            half8 hv;
            #pragma unroll
            for (int e = 0; e < 6; ++e) hv[e] = (_Float16)v[32 + e];
            hv[6] = (_Float16)0.0f; hv[7] = (_Float16)0.0f;
            *(half8*)(dst + 32) = hv;
            // dst[40..47] stay zero from the memset
        }
    }

    // ---- persistent weight fragments (1 col-triple per wave) ----
    half8 wh[3][4];    // enc: eWhh | dec: r/z combined, n pure dWhh
    half8 wxe[3][2];   // encoder Wih (K padded 38->64); dead after encoder
    half8 wxn[4];      // decoder n-gate W2
    half8 wl[4];       // linear head
    float b_r, b_z, b_ngi, b_ngh;

    #pragma unroll
    for (int p = 0; p < 3; ++p) {
        const int jp = p * H_DIM + j;
        const float* wr = eWhh + (size_t)jp * H_DIM;
        #pragma unroll
        for (int c = 0; c < 4; ++c) {
            const int kb = c * 32 + quad * 8;
            half8 v;
            #pragma unroll
            for (int e = 0; e < 8; ++e) v[e] = (_Float16)wr[kb + e];
            wh[p][c] = v;
        }
        const float* wir = eWih + (size_t)jp * X_DIM;
        #pragma unroll
        for (int c = 0; c < 2; ++c) {
            const int kb = c * 32 + quad * 8;
            half8 v;
            #pragma unroll
            for (int e = 0; e < 8; ++e) {
                const int k = kb + e;
                v[e] = (k < X_DIM) ? (_Float16)wir[k] : (_Float16)0.0f;
            }
            wxe[p][c] = v;
        }
    }
    b_r   = ebih[jc0] + ebhh[jc0];
    b_z   = ebih[jc1] + ebhh[jc1];
    b_ngi = ebih[jc2];
    b_ngh = ebhh[jc2];

    float hold = 0.0f;   // h[quad][j] in fp32

    __syncthreads();     // staging complete before first encoder read

    // ================= encoder =================
    #pragma unroll 1
    for (int t = 0; t < T_SEQ; ++t) {
        const _Float16* hrd = hbuf + (t & 1) * (BT * HS);
        _Float16*       hwr = hbuf + ((t & 1) ^ 1) * (BT * HS);
        const _Float16* xrow = xlds + t * (BT * XK) + arow * XK;

        half8 xa0 = *(const half8*)(xrow + quad * 8);
        half8 xa1 = xa0;                       // quads 1-3: finite, zero weights
        if (quad == 0) xa1 = *(const half8*)(xrow + 32);

        // r/z: gi merged into the gh accumulator; n split (r scales gh_n only)
        f32x4 accr = { b_r, b_r, b_r, b_r };
        accr = __builtin_amdgcn_mfma_f32_16x16x32_f16(xa0, wxe[0][0], accr, 0, 0, 0);
        accr = __builtin_amdgcn_mfma_f32_16x16x32_f16(xa1, wxe[0][1], accr, 0, 0, 0);
        f32x4 accz = { b_z, b_z, b_z, b_z };
        accz = __builtin_amdgcn_mfma_f32_16x16x32_f16(xa0, wxe[1][0], accz, 0, 0, 0);
        accz = __builtin_amdgcn_mfma_f32_16x16x32_f16(xa1, wxe[1][1], accz, 0, 0, 0);
        f32x4 gin = { b_ngi, b_ngi, b_ngi, b_ngi };
        gin = __builtin_amdgcn_mfma_f32_16x16x32_f16(xa0, wxe[2][0], gin, 0, 0, 0);
        gin = __builtin_amdgcn_mfma_f32_16x16x32_f16(xa1, wxe[2][1], gin, 0, 0, 0);

        f32x4 ghn = { b_ngh, b_ngh, b_ngh, b_ngh };
        #pragma unroll
        for (int c = 0; c < 4; ++c) {
            half8 hc = *(const half8*)&hrd[arow * HS + c * 32 + quad * 8];
            accr = __builtin_amdgcn_mfma_f32_16x16x32_f16(hc, wh[0][c], accr, 0, 0, 0);
            accz = __builtin_amdgcn_mfma_f32_16x16x32_f16(hc, wh[1][c], accz, 0, 0, 0);
            ghn  = __builtin_amdgcn_mfma_f32_16x16x32_f16(hc, wh[2][c], ghn, 0, 0, 0);
        }

        // single valid C element: reg 0 -> batch = quad, col = j
        const float r = fast_sigmoid(accr[0]);
        const float z = fast_sigmoid(accz[0]);
        const float n = fast_tanh(gin[0] + r * ghn[0]);
        const float h = n + z * (hold - n);
        hold = h;
        hwr[quad * HS + j] = (_Float16)h;

        __syncthreads();
    }

    // ================= decoder weight prep =================
    // Step A: pure dWhh frags + biases.
    #pragma unroll
    for (int p = 0; p < 3; ++p) {
        const float* wr = dWhh + (size_t)(p * H_DIM + j) * H_DIM;
        #pragma unroll
        for (int c = 0; c < 4; ++c) {
            const int kb = c * 32 + quad * 8;
            half8 v;
            #pragma unroll
            for (int e = 0; e < 8; ++e) v[e] = (_Float16)wr[kb + e];
            wh[p][c] = v;
        }
    }
    const float c_r0 = dbih[jc0] + dbhh[jc0];
    const float c_z0 = dbih[jc1] + dbhh[jc1];
    const float c_n0 = dbih[jc2];
    b_ngh = dbhh[jc2];

    // Step B: t=0 pre-step (gi = bias only). h_enc in hbuf[0] -> d_1 to hbuf[1].
    {
        const _Float16* hrd = hbuf;
        _Float16*       hwr = hbuf + BT * HS;
        f32x4 ar = { c_r0, c_r0, c_r0, c_r0 };
        f32x4 az = { c_z0, c_z0, c_z0, c_z0 };
        f32x4 aghn = { b_ngh, b_ngh, b_ngh, b_ngh };
        #pragma unroll
        for (int c = 0; c < 4; ++c) {
            half8 hc = *(const half8*)&hrd[arow * HS + c * 32 + quad * 8];
            ar   = __builtin_amdgcn_mfma_f32_16x16x32_f16(hc, wh[0][c], ar, 0, 0, 0);
            az   = __builtin_amdgcn_mfma_f32_16x16x32_f16(hc, wh[1][c], az, 0, 0, 0);
            aghn = __builtin_amdgcn_mfma_f32_16x16x32_f16(hc, wh[2][c], aghn, 0, 0, 0);
        }
        const float r = fast_sigmoid(ar[0]);
        const float z = fast_sigmoid(az[0]);
        const float n = fast_tanh(c_n0 + r * aghn[0]);
        const float h = n + z * (hold - n);
        hold = h;
        hwr[quad * HS + j] = (_Float16)h;
    }
    __syncthreads();

    // Step C: fold W2 = dWih*linW. r/z: wh <- fp16(dWhh + W2); n: wxn <- fp16(W2).
    // (w2lds aliases xlds; x is dead.)
    {
        const int kk = ((wv & 1) << 6) | ln;      // 0..127, lane's W2 column
        const int jb = (wv >> 1) * 32;            // 4 wave-pairs x 32 rows = 128
        float lc[X_DIM];
        #pragma unroll
        for (int m = 0; m < X_DIM; ++m) lc[m] = linW[m * H_DIM + kk];

        // gate 0 (r): combined
        #pragma unroll 1
        for (int jj = 0; jj < 32; ++jj) {
            const int jr = __builtin_amdgcn_readfirstlane(jb + jj);
            const float* dwr = dWih + (size_t)jr * X_DIM;
            float sacc = dWhh[(size_t)jr * H_DIM + kk];
            #pragma unroll
            for (int m = 0; m < X_DIM; ++m) sacc += dwr[m] * lc[m];
            w2lds[jr * H_DIM + kk] = (_Float16)sacc;
        }
        __syncthreads();
        #pragma unroll
        for (int c = 0; c < 4; ++c)
            wh[0][c] = *(const half8*)&w2lds[j * H_DIM + c * 32 + quad * 8];
        __syncthreads();

        // gate 1 (z): combined
        #pragma unroll 1
        for (int jj = 0; jj < 32; ++jj) {
            const int jr = __builtin_amdgcn_readfirstlane(jb + jj);
            const float* dwr = dWih + (size_t)(H_DIM + jr) * X_DIM;
            float sacc = dWhh[(size_t)(H_DIM + jr) * H_DIM + kk];
            #pragma unroll
            for (int m = 0; m < X_DIM; ++m) sacc += dwr[m] * lc[m];
            w2lds[jr * H_DIM + kk] = (_Float16)sacc;
        }
        __syncthreads();
        #pragma unroll
        for (int c = 0; c < 4; ++c)
            wh[1][c] = *(const half8*)&w2lds[j * H_DIM + c * 32 + quad * 8];
        __syncthreads();

        // gate 2 (n): W2 only (wh[2] stays pure dWhh)
        #pragma unroll 1
        for (int jj = 0; jj < 32; ++jj) {
            const int jr = __builtin_amdgcn_readfirstlane(jb + jj);
            const float* dwr = dWih + (size_t)(2 * H_DIM + jr) * X_DIM;
            float sacc = 0.0f;
            #pragma unroll
            for (int m = 0; m < X_DIM; ++m) sacc += dwr[m] * lc[m];
            w2lds[jr * H_DIM + kk] = (_Float16)sacc;
        }
        __syncthreads();
        #pragma unroll
        for (int c = 0; c < 4; ++c)
            wxn[c] = *(const half8*)&w2lds[j * H_DIM + c * 32 + quad * 8];
        __syncthreads();
    }

    // Step D: linear head frags + folded biases for t>=1.
    const int nlin = wv * 16 + mrow;          // waves 0..2 cover cols 0..47
    const bool nv = (wv < 3) && (nlin < X_DIM);
    float lb = 0.0f;
    {
        const float* lr = linW + (size_t)(nv ? nlin : 0) * H_DIM;
        #pragma unroll
        for (int c = 0; c < 4; ++c) {
            const int kb = c * 32 + quad * 8;
            half8 v;
            #pragma unroll
            for (int e = 0; e < 8; ++e)
                v[e] = nv ? (_Float16)lr[kb + e] : (_Float16)0.0f;
            wl[c] = v;
        }
        if (nv) lb = linb[nlin];
    }
    {
        float bf[3];
        #pragma unroll
        for (int p = 0; p < 3; ++p) {
            const float* dwr = dWih + (size_t)(p * H_DIM + j) * X_DIM;
            float sacc = 0.0f;
            #pragma unroll
            for (int m = 0; m < X_DIM; ++m) sacc += linb[m] * dwr[m];
            bf[p] = sacc;
        }
        b_r   = c_r0 + bf[0];
        b_z   = c_z0 + bf[1];
        b_ngi = c_n0 + bf[2];
    }

    const unsigned obase = (unsigned)((b0 + quad) * T_SEQ) * X_DIM + (unsigned)nlin;

    // ================= decoder (t=1..127) ========
    #pragma unroll 1
    for (int t = 1; t < T_SEQ; ++t) {
        const _Float16* hrd = hbuf + (t & 1) * (BT * HS);
        _Float16*       hwr = hbuf + ((t & 1) ^ 1) * (BT * HS);

        f32x4 ar = { b_r, b_r, b_r, b_r };
        f32x4 az = { b_z, b_z, b_z, b_z };
        f32x4 aghn = { b_ngh, b_ngh, b_ngh, b_ngh };
        f32x4 agin = { b_ngi, b_ngi, b_ngi, b_ngi };
        f32x4 al = { lb, lb, lb, lb };
        #pragma unroll
        for (int c = 0; c < 4; ++c) {
            half8 hc = *(const half8*)&hrd[arow * HS + c * 32 + quad * 8];
            if (wv < 3)
                al = __builtin_amdgcn_mfma_f32_16x16x32_f16(hc, wl[c], al, 0, 0, 0);
            ar   = __builtin_amdgcn_mfma_f32_16x16x32_f16(hc, wh[0][c], ar, 0, 0, 0);
            az   = __builtin_amdgcn_mfma_f32_16x16x32_f16(hc, wh[1][c], az, 0, 0, 0);
            aghn = __builtin_amdgcn_mfma_f32_16x16x32_f16(hc, wh[2][c], aghn, 0, 0, 0);
            agin = __builtin_amdgcn_mfma_f32_16x16x32_f16(hc, wxn[c],  agin, 0, 0, 0);
        }

        // overlapped output projection: o_{t-1} = d_t @ linW^T + lb
        // (store issued ~400cy before the barrier -> L2 ack hidden)
        if (nv)
            out[obase + (unsigned)(t - 1) * X_DIM] = al[0];

        const float r = fast_sigmoid(ar[0]);
        const float z = fast_sigmoid(az[0]);
        const float n = fast_tanh(agin[0] + r * aghn[0]);
        const float h = n + z * (hold - n);
        hold = h;
        hwr[quad * HS + j] = (_Float16)h;

        __syncthreads();
    }

    // tail projection: o_{T-1} = d_128 @ linW^T + lb (d_128 in hbuf[0])
    if (wv < 3) {
        const _Float16* hrd = hbuf;
        f32x4 al = { lb, lb, lb, lb };
        #pragma unroll
        for (int c = 0; c < 4; ++c) {
            half8 hc = *(const half8*)&hrd[arow * HS + c * 32 + quad * 8];
            al = __builtin_amdgcn_mfma_f32_16x16x32_f16(hc, wl[c], al, 0, 0, 0);
        }
        if (nv)
            out[obase + (unsigned)(T_SEQ - 1) * X_DIM] = al[0];
    }
}

extern "C" void kernel_launch(void* const* d_in, const int* in_sizes, int n_in,
                              void* d_out, int out_size, void* d_ws, size_t ws_size,
                              hipStream_t stream) {
    (void)in_sizes; (void)n_in; (void)d_ws; (void)ws_size; (void)out_size;
    const float* x    = (const float*)d_in[0];
    const float* eWih = (const float*)d_in[1];
    const float* eWhh = (const float*)d_in[2];
    const float* ebih = (const float*)d_in[3];
    const float* ebhh = (const float*)d_in[4];
    const float* dWih = (const float*)d_in[5];
    const float* dWhh = (const float*)d_in[6];
    const float* dbih = (const float*)d_in[7];
    const float* dbhh = (const float*)d_in[8];
    const float* linW = (const float*)d_in[9];
    const float* linb = (const float*)d_in[10];
    float* out = (float*)d_out;

    rae_gru_kernel<<<dim3(B_TOT / BT), dim3(512), 0, stream>>>(
        x, eWih, eWhh, ebih, ebhh, dWih, dWhh, dbih, dbhh, linW, linb, out);
}

// Round 3
// 297.474 us; speedup vs baseline: 1.4042x; 1.4042x over previous
//
#include <hip/hip_runtime.h>
#include <cstdint>

// GRU recurrent autoencoder, MI355X persistent-MFMA implementation, round 10.
// B=2048, T=128, X=38, H=128, 3H=384. fp32 I/O, fp16 MFMA operands,
// fp32 accumulation + fp32 recurrent state (in registers).
//
// Round 10 = r7 config (BT=8, grid 256, dup=2) + r9 safety + step grinding.
//   Calibration from r9: one 16x16x32 f16 MFMA occupies a SIMD ~19.4 cyc
//   (2075 TF ubench / 256 CU / 4 SIMD). r9's BT=4 (dup x4) doubled chip MFMA
//   work; its occupancy win was eaten (294 -> 375us). 2048 B / 256 CU = 8
//   batches/CU vs min M-tile 16 -> dup=2 is the forced optimum (r7 config).
// Step-time levers this round (r7 idle ~50%, VALU 30%):
//  * x staged to LDS fp16 in two 64-t chunks [t][8][40] (40KB; row stride
//    80B -> 8 rows on distinct banks). Kills the register x-pipeline's
//    ~40 VALU/wave/step (rotation+cvt) and makes encoder __syncthreads
//    vmcnt-free (zero global ops in the loop).
//  * Balanced MFMA chains: each gate split into two independent 3- or
//    2-deep chains (+1 epilogue add) instead of 6/4-deep -> recurrence
//    critical path roughly halves. Decoder proj split 2+2, store earlier.
//  * 2-step unroll with hardcoded ping-pong h buffers: no parity selects.
//  * HS=136 (68 dw == 4 mod 32): all 8 h rows start on distinct bank
//    quads -> conflict-free b128 h reads (160 would be 4-way at 8 rows).
//  * __syncthreads everywhere (r8's replay-race class stays dead).
//  * Decoder algebra unchanged (r/z folded dWhh+dWih*linW, n-gate W2
//    separate, projection overlapped, t=0 pre-step).

#define T_SEQ 128
#define X_DIM 38
#define H_DIM 128
#define B_TOT 2048
#define BT    8
#define HS    136   // h row stride in halfs: 68 dw == 4 mod 32 -> 8-row spread
#define XK    40    // x row stride in halfs: 20 dw == 20 mod 32 -> 8-row spread
#define XCH   64    // x chunk length (timesteps)

#define HB_BYTES   (2 * BT * HS * 2)        // 4352
#define XC_BYTES   (XCH * BT * XK * 2)      // 40960 (>= 32768 w2lds alias)
#define SMEM_BYTES (HB_BYTES + XC_BYTES)    // 45312

typedef _Float16 half8 __attribute__((ext_vector_type(8)));
typedef float    f32x4 __attribute__((ext_vector_type(4)));

#define MF(a, b, c) __builtin_amdgcn_mfma_f32_16x16x32_f16((a), (b), (c), 0, 0, 0)

__device__ __forceinline__ float fast_sigmoid(float x) {
    return __builtin_amdgcn_rcpf(1.0f + __expf(-x));
}
__device__ __forceinline__ float fast_tanh(float x) {
    return 1.0f - 2.0f * __builtin_amdgcn_rcpf(1.0f + __expf(2.0f * x));
}

// ---- encoder step: read h from HRD, x from xchunk[TLOC], write h to HWR ----
#define ENC_STEP(HRD, HWR, TLOC)                                               \
    do {                                                                       \
        const _Float16* xr_ = xchunk + ((TLOC) * BT + arow) * XK;              \
        half8 xa0_ = *(const half8*)(xr_ + quad * 8);                          \
        half8 xa1_ = xa0_;            /* quads 1-3: finite vs zero weights */  \
        if (quad == 0) xa1_ = *(const half8*)(xr_ + 32);                       \
        const _Float16* hb_ = (HRD) + arow * HS + quad * 8;                    \
        half8 h0_ = *(const half8*)(hb_ + 0 * 32);                             \
        half8 h1_ = *(const half8*)(hb_ + 1 * 32);                             \
        half8 h2_ = *(const half8*)(hb_ + 2 * 32);                             \
        half8 h3_ = *(const half8*)(hb_ + 3 * 32);                             \
        f32x4 ar_ = { b_r, b_r, b_r, b_r };                                    \
        ar_ = MF(xa0_, wxe[0][0], ar_);                                        \
        ar_ = MF(xa1_, wxe[0][1], ar_);                                        \
        ar_ = MF(h0_, wh[0][0], ar_);                                          \
        f32x4 arB_ = { 0.f, 0.f, 0.f, 0.f };                                   \
        arB_ = MF(h1_, wh[0][1], arB_);                                        \
        arB_ = MF(h2_, wh[0][2], arB_);                                        \
        arB_ = MF(h3_, wh[0][3], arB_);                                        \
        f32x4 az_ = { b_z, b_z, b_z, b_z };                                    \
        az_ = MF(xa0_, wxe[1][0], az_);                                        \
        az_ = MF(xa1_, wxe[1][1], az_);                                        \
        az_ = MF(h0_, wh[1][0], az_);                                          \
        f32x4 azB_ = { 0.f, 0.f, 0.f, 0.f };                                   \
        azB_ = MF(h1_, wh[1][1], azB_);                                        \
        azB_ = MF(h2_, wh[1][2], azB_);                                        \
        azB_ = MF(h3_, wh[1][3], azB_);                                        \
        f32x4 gin_ = { b_ngi, b_ngi, b_ngi, b_ngi };                           \
        gin_ = MF(xa0_, wxe[2][0], gin_);                                      \
        gin_ = MF(xa1_, wxe[2][1], gin_);                                      \
        f32x4 gn_ = { b_ngh, b_ngh, b_ngh, b_ngh };                            \
        gn_ = MF(h0_, wh[2][0], gn_);                                          \
        gn_ = MF(h1_, wh[2][1], gn_);                                          \
        f32x4 gnB_ = { 0.f, 0.f, 0.f, 0.f };                                   \
        gnB_ = MF(h2_, wh[2][2], gnB_);                                        \
        gnB_ = MF(h3_, wh[2][3], gnB_);                                        \
        _Pragma("unroll")                                                      \
        for (int e_ = 0; e_ < 2; ++e_) {                                       \
            const int rg_ = 2 * e_;   /* valid C rows: reg 0 / reg 2 */        \
            const float r_ = fast_sigmoid(ar_[rg_] + arB_[rg_]);               \
            const float z_ = fast_sigmoid(az_[rg_] + azB_[rg_]);               \
            const float n_ = fast_tanh(gin_[rg_] + r_ * (gn_[rg_] + gnB_[rg_]));\
            const float h_ = n_ + z_ * (hold[e_] - n_);                        \
            hold[e_] = h_;                                                     \
            (HWR)[(2 * quad + e_) * HS + j] = (_Float16)h_;                    \
        }                                                                      \
        __syncthreads();                                                       \
    } while (0)

// ---- decoder step: read d_t from HRD, write d_{t+1} to HWR, store o at TOUT --
#define DEC_STEP(HRD, HWR, TOUT)                                               \
    do {                                                                       \
        const _Float16* hb_ = (HRD) + arow * HS + quad * 8;                    \
        half8 h0_ = *(const half8*)(hb_ + 0 * 32);                             \
        half8 h1_ = *(const half8*)(hb_ + 1 * 32);                             \
        half8 h2_ = *(const half8*)(hb_ + 2 * 32);                             \
        half8 h3_ = *(const half8*)(hb_ + 3 * 32);                             \
        if (wv < 3) {   /* o_{TOUT} = d @ linW^T + lb, split 2+2, store early */\
            f32x4 al_ = { lb, lb, lb, lb };                                    \
            al_ = MF(h0_, wl[0], al_);                                         \
            al_ = MF(h1_, wl[1], al_);                                         \
            f32x4 alB_ = { 0.f, 0.f, 0.f, 0.f };                               \
            alB_ = MF(h2_, wl[2], alB_);                                       \
            alB_ = MF(h3_, wl[3], alB_);                                       \
            if (nv) {                                                          \
                out[obase0 + (size_t)(TOUT) * X_DIM] = al_[0] + alB_[0];       \
                out[obase1 + (size_t)(TOUT) * X_DIM] = al_[2] + alB_[2];       \
            }                                                                  \
        }                                                                      \
        f32x4 ar_ = { b_r, b_r, b_r, b_r };                                    \
        ar_ = MF(h0_, wh[0][0], ar_);                                          \
        ar_ = MF(h1_, wh[0][1], ar_);                                          \
        f32x4 arB_ = { 0.f, 0.f, 0.f, 0.f };                                   \
        arB_ = MF(h2_, wh[0][2], arB_);                                        \
        arB_ = MF(h3_, wh[0][3], arB_);                                        \
        f32x4 az_ = { b_z, b_z, b_z, b_z };                                    \
        az_ = MF(h0_, wh[1][0], az_);                                          \
        az_ = MF(h1_, wh[1][1], az_);                                          \
        f32x4 azB_ = { 0.f, 0.f, 0.f, 0.f };                                   \
        azB_ = MF(h2_, wh[1][2], azB_);                                        \
        azB_ = MF(h3_, wh[1][3], azB_);                                        \
        f32x4 gn_ = { b_ngh, b_ngh, b_ngh, b_ngh };                            \
        gn_ = MF(h0_, wh[2][0], gn_);                                          \
        gn_ = MF(h1_, wh[2][1], gn_);                                          \
        f32x4 gnB_ = { 0.f, 0.f, 0.f, 0.f };                                   \
        gnB_ = MF(h2_, wh[2][2], gnB_);                                        \
        gnB_ = MF(h3_, wh[2][3], gnB_);                                        \
        f32x4 gi_ = { b_ngi, b_ngi, b_ngi, b_ngi };                            \
        gi_ = MF(h0_, wxn[0], gi_);                                            \
        gi_ = MF(h1_, wxn[1], gi_);                                            \
        f32x4 giB_ = { 0.f, 0.f, 0.f, 0.f };                                   \
        giB_ = MF(h2_, wxn[2], giB_);                                          \
        giB_ = MF(h3_, wxn[3], giB_);                                          \
        _Pragma("unroll")                                                      \
        for (int e_ = 0; e_ < 2; ++e_) {                                       \
            const int rg_ = 2 * e_;                                            \
            const float r_ = fast_sigmoid(ar_[rg_] + arB_[rg_]);               \
            const float z_ = fast_sigmoid(az_[rg_] + azB_[rg_]);               \
            const float n_ = fast_tanh((gi_[rg_] + giB_[rg_]) +                \
                                       r_ * (gn_[rg_] + gnB_[rg_]));           \
            const float h_ = n_ + z_ * (hold[e_] - n_);                        \
            hold[e_] = h_;                                                     \
            (HWR)[(2 * quad + e_) * HS + j] = (_Float16)h_;                    \
        }                                                                      \
        __syncthreads();                                                       \
    } while (0)

__global__ __launch_bounds__(512, 2)
void rae_gru_kernel(const float* __restrict__ x,
                    const float* __restrict__ eWih, const float* __restrict__ eWhh,
                    const float* __restrict__ ebih, const float* __restrict__ ebhh,
                    const float* __restrict__ dWih, const float* __restrict__ dWhh,
                    const float* __restrict__ dbih, const float* __restrict__ dbhh,
                    const float* __restrict__ linW, const float* __restrict__ linb,
                    float* __restrict__ out)
{
    __shared__ __align__(16) unsigned char smem[SMEM_BYTES];
    _Float16* const hbuf0  = (_Float16*)smem;                 // [BT][HS]
    _Float16* const hbuf1  = hbuf0 + BT * HS;                 // [BT][HS]
    _Float16* const xchunk = (_Float16*)(smem + HB_BYTES);    // [XCH][BT][XK]
    _Float16* const w2lds  = xchunk;                          // [128][128] alias (x dead)

    const int tid  = threadIdx.x;
    const int wv   = tid >> 6;        // 0..7
    const int ln   = tid & 63;
    const int quad = ln >> 4;         // A/B: k-group; C: row-group
    const int mrow = ln & 15;         // A: m-row / B,C: col-in-tile
    const int b0   = blockIdx.x * BT;
    const int arow = mrow >> 1;       // batch row this A-lane reads (b at m=2b)
    const int j    = wv * 16 + mrow;  // this lane's gate column (8 waves x 16)
    const int jc0  = j, jc1 = H_DIM + j, jc2 = 2 * H_DIM + j;

    {   // zero h buffers (h0 = 0)
        uint32_t* hz = (uint32_t*)smem;
        #pragma unroll
        for (int i = tid; i < HB_BYTES / 4; i += 512) hz[i] = 0u;
    }

    // ---- x chunk staging: 512 thr = 64 t x 8 rows, fp16 [t][row][XK] ----
    auto stage_x = [&](int tb) {
        const int st = tid & 63, sr = tid >> 6;
        const float* src = x + ((size_t)(b0 + sr) * T_SEQ + tb + st) * X_DIM;
        _Float16* dst = xchunk + ((size_t)st * BT + sr) * XK;
        float v[38];
        #pragma unroll
        for (int u = 0; u < 19; ++u) {
            float2 w = *(const float2*)(src + 2 * u);
            v[2 * u] = w.x; v[2 * u + 1] = w.y;
        }
        #pragma unroll
        for (int c = 0; c < 4; ++c) {
            half8 hv;
            #pragma unroll
            for (int e = 0; e < 8; ++e) hv[e] = (_Float16)v[c * 8 + e];
            *(half8*)(dst + c * 8) = hv;
        }
        {
            half8 hv;
            #pragma unroll
            for (int e = 0; e < 6; ++e) hv[e] = (_Float16)v[32 + e];
            hv[6] = (_Float16)0.0f; hv[7] = (_Float16)0.0f;
            *(half8*)(dst + 32) = hv;
        }
    };
    stage_x(0);

    // ---- persistent weight fragments (1 col-triple per wave) ----
    half8 wh[3][4];    // enc: eWhh | dec: r/z combined, n pure dWhh
    half8 wxe[3][2];   // encoder Wih (K padded 38->64); dead after encoder
    half8 wxn[4];      // decoder n-gate W2
    half8 wl[4];       // linear head
    float b_r, b_z, b_ngi, b_ngh;

    #pragma unroll
    for (int p = 0; p < 3; ++p) {
        const int jp = p * H_DIM + j;
        const float* wr = eWhh + (size_t)jp * H_DIM;
        #pragma unroll
        for (int c = 0; c < 4; ++c) {
            const int kb = c * 32 + quad * 8;
            half8 v;
            #pragma unroll
            for (int e = 0; e < 8; ++e) v[e] = (_Float16)wr[kb + e];
            wh[p][c] = v;
        }
        const float* wir = eWih + (size_t)jp * X_DIM;
        #pragma unroll
        for (int c = 0; c < 2; ++c) {
            const int kb = c * 32 + quad * 8;
            half8 v;
            #pragma unroll
            for (int e = 0; e < 8; ++e) {
                const int k = kb + e;
                v[e] = (k < X_DIM) ? (_Float16)wir[k] : (_Float16)0.0f;
            }
            wxe[p][c] = v;
        }
    }
    b_r   = ebih[jc0] + ebhh[jc0];
    b_z   = ebih[jc1] + ebhh[jc1];
    b_ngi = ebih[jc2];
    b_ngh = ebhh[jc2];

    float hold[2] = { 0.0f, 0.0f };   // h[2quad+e][j] in fp32

    __syncthreads();     // staging + h-zero complete

    // ================= encoder (2 chunks x 32 unrolled pairs) =============
    #pragma unroll 1
    for (int i = 0; i < 32; ++i) {
        ENC_STEP(hbuf0, hbuf1, 2 * i);
        ENC_STEP(hbuf1, hbuf0, 2 * i + 1);
    }
    stage_x(XCH);
    __syncthreads();
    #pragma unroll 1
    for (int i = 0; i < 32; ++i) {
        ENC_STEP(hbuf0, hbuf1, 2 * i);
        ENC_STEP(hbuf1, hbuf0, 2 * i + 1);
    }
    // h_enc now in hbuf0

    // ================= decoder weight prep =================
    // Step A: pure dWhh frags + biases.
    #pragma unroll
    for (int p = 0; p < 3; ++p) {
        const float* wr = dWhh + (size_t)(p * H_DIM + j) * H_DIM;
        #pragma unroll
        for (int c = 0; c < 4; ++c) {
            const int kb = c * 32 + quad * 8;
            half8 v;
            #pragma unroll
            for (int e = 0; e < 8; ++e) v[e] = (_Float16)wr[kb + e];
            wh[p][c] = v;
        }
    }
    const float c_r0 = dbih[jc0] + dbhh[jc0];
    const float c_z0 = dbih[jc1] + dbhh[jc1];
    const float c_n0 = dbih[jc2];
    b_ngh = dbhh[jc2];

    // Step B: t=0 pre-step (gi = bias only). h_enc in hbuf0 -> d_1 to hbuf1.
    {
        const _Float16* hb_ = hbuf0 + arow * HS + quad * 8;
        half8 h0_ = *(const half8*)(hb_ + 0 * 32);
        half8 h1_ = *(const half8*)(hb_ + 1 * 32);
        half8 h2_ = *(const half8*)(hb_ + 2 * 32);
        half8 h3_ = *(const half8*)(hb_ + 3 * 32);
        f32x4 ar_ = { c_r0, c_r0, c_r0, c_r0 };
        ar_ = MF(h0_, wh[0][0], ar_);
        ar_ = MF(h1_, wh[0][1], ar_);
        f32x4 arB_ = { 0.f, 0.f, 0.f, 0.f };
        arB_ = MF(h2_, wh[0][2], arB_);
        arB_ = MF(h3_, wh[0][3], arB_);
        f32x4 az_ = { c_z0, c_z0, c_z0, c_z0 };
        az_ = MF(h0_, wh[1][0], az_);
        az_ = MF(h1_, wh[1][1], az_);
        f32x4 azB_ = { 0.f, 0.f, 0.f, 0.f };
        azB_ = MF(h2_, wh[1][2], azB_);
        azB_ = MF(h3_, wh[1][3], azB_);
        f32x4 gn_ = { b_ngh, b_ngh, b_ngh, b_ngh };
        gn_ = MF(h0_, wh[2][0], gn_);
        gn_ = MF(h1_, wh[2][1], gn_);
        f32x4 gnB_ = { 0.f, 0.f, 0.f, 0.f };
        gnB_ = MF(h2_, wh[2][2], gnB_);
        gnB_ = MF(h3_, wh[2][3], gnB_);
        #pragma unroll
        for (int e_ = 0; e_ < 2; ++e_) {
            const int rg_ = 2 * e_;
            const float r_ = fast_sigmoid(ar_[rg_] + arB_[rg_]);
            const float z_ = fast_sigmoid(az_[rg_] + azB_[rg_]);
            const float n_ = fast_tanh(c_n0 + r_ * (gn_[rg_] + gnB_[rg_]));
            const float h_ = n_ + z_ * (hold[e_] - n_);
            hold[e_] = h_;
            hbuf1[(2 * quad + e_) * HS + j] = (_Float16)h_;
        }
    }
    __syncthreads();

    // Step C: fold W2 = dWih*linW. r/z: wh <- fp16(dWhh + W2); n: wxn <- fp16(W2).
    // (w2lds aliases xchunk; x is dead.)
    {
        const int kk = ((wv & 1) << 6) | ln;      // 0..127, lane's W2 column
        const int jb = (wv >> 1) * 32;            // 4 wave-pairs x 32 rows = 128
        float lc[X_DIM];
        #pragma unroll
        for (int m = 0; m < X_DIM; ++m) lc[m] = linW[m * H_DIM + kk];

        // gate 0 (r): combined
        #pragma unroll 1
        for (int jj = 0; jj < 32; ++jj) {
            const int jr = __builtin_amdgcn_readfirstlane(jb + jj);
            const float* dwr = dWih + (size_t)jr * X_DIM;
            float sacc = dWhh[(size_t)jr * H_DIM + kk];
            #pragma unroll
            for (int m = 0; m < X_DIM; ++m) sacc += dwr[m] * lc[m];
            w2lds[jr * H_DIM + kk] = (_Float16)sacc;
        }
        __syncthreads();
        #pragma unroll
        for (int c = 0; c < 4; ++c)
            wh[0][c] = *(const half8*)&w2lds[j * H_DIM + c * 32 + quad * 8];
        __syncthreads();

        // gate 1 (z): combined
        #pragma unroll 1
        for (int jj = 0; jj < 32; ++jj) {
            const int jr = __builtin_amdgcn_readfirstlane(jb + jj);
            const float* dwr = dWih + (size_t)(H_DIM + jr) * X_DIM;
            float sacc = dWhh[(size_t)(H_DIM + jr) * H_DIM + kk];
            #pragma unroll
            for (int m = 0; m < X_DIM; ++m) sacc += dwr[m] * lc[m];
            w2lds[jr * H_DIM + kk] = (_Float16)sacc;
        }
        __syncthreads();
        #pragma unroll
        for (int c = 0; c < 4; ++c)
            wh[1][c] = *(const half8*)&w2lds[j * H_DIM + c * 32 + quad * 8];
        __syncthreads();

        // gate 2 (n): W2 only (wh[2] stays pure dWhh)
        #pragma unroll 1
        for (int jj = 0; jj < 32; ++jj) {
            const int jr = __builtin_amdgcn_readfirstlane(jb + jj);
            const float* dwr = dWih + (size_t)(2 * H_DIM + jr) * X_DIM;
            float sacc = 0.0f;
            #pragma unroll
            for (int m = 0; m < X_DIM; ++m) sacc += dwr[m] * lc[m];
            w2lds[jr * H_DIM + kk] = (_Float16)sacc;
        }
        __syncthreads();
        #pragma unroll
        for (int c = 0; c < 4; ++c)
            wxn[c] = *(const half8*)&w2lds[j * H_DIM + c * 32 + quad * 8];
        __syncthreads();
    }

    // Step D: linear head frags + folded biases for t>=1.
    const int nlin = wv * 16 + mrow;          // waves 0..2 cover cols 0..47
    const bool nv = (wv < 3) && (nlin < X_DIM);
    float lb = 0.0f;
    {
        const float* lr = linW + (size_t)(nv ? nlin : 0) * H_DIM;
        #pragma unroll
        for (int c = 0; c < 4; ++c) {
            const int kb = c * 32 + quad * 8;
            half8 v;
            #pragma unroll
            for (int e = 0; e < 8; ++e)
                v[e] = nv ? (_Float16)lr[kb + e] : (_Float16)0.0f;
            wl[c] = v;
        }
        if (nv) lb = linb[nlin];
    }
    {
        float bf[3];
        #pragma unroll
        for (int p = 0; p < 3; ++p) {
            const float* dwr = dWih + (size_t)(p * H_DIM + j) * X_DIM;
            float sacc = 0.0f;
            #pragma unroll
            for (int m = 0; m < X_DIM; ++m) sacc += linb[m] * dwr[m];
            bf[p] = sacc;
        }
        b_r   = c_r0 + bf[0];
        b_z   = c_z0 + bf[1];
        b_ngi = c_n0 + bf[2];
    }

    const size_t obase0 = ((size_t)(b0 + 2 * quad)     * T_SEQ) * X_DIM + nlin;
    const size_t obase1 = ((size_t)(b0 + 2 * quad + 1) * T_SEQ) * X_DIM + nlin;

    // ================= decoder (t=1..127, 63 unrolled pairs + tail) ========
    #pragma unroll 1
    for (int i = 0; i < 63; ++i) {
        DEC_STEP(hbuf1, hbuf0, 2 * i);        // t = 2i+1, stores o_{2i}
        DEC_STEP(hbuf0, hbuf1, 2 * i + 1);    // t = 2i+2, stores o_{2i+1}
    }
    DEC_STEP(hbuf1, hbuf0, 126);              // t = 127, stores o_126; d_128 -> hbuf0

    // tail projection: o_127 = d_128 @ linW^T + lb (d_128 in hbuf0)
    if (wv < 3) {
        const _Float16* hb_ = hbuf0 + arow * HS + quad * 8;
        half8 h0_ = *(const half8*)(hb_ + 0 * 32);
        half8 h1_ = *(const half8*)(hb_ + 1 * 32);
        half8 h2_ = *(const half8*)(hb_ + 2 * 32);
        half8 h3_ = *(const half8*)(hb_ + 3 * 32);
        f32x4 al_ = { lb, lb, lb, lb };
        al_ = MF(h0_, wl[0], al_);
        al_ = MF(h1_, wl[1], al_);
        f32x4 alB_ = { 0.f, 0.f, 0.f, 0.f };
        alB_ = MF(h2_, wl[2], alB_);
        alB_ = MF(h3_, wl[3], alB_);
        if (nv) {
            out[obase0 + (size_t)(T_SEQ - 1) * X_DIM] = al_[0] + alB_[0];
            out[obase1 + (size_t)(T_SEQ - 1) * X_DIM] = al_[2] + alB_[2];
        }
    }
}

extern "C" void kernel_launch(void* const* d_in, const int* in_sizes, int n_in,
                              void* d_out, int out_size, void* d_ws, size_t ws_size,
                              hipStream_t stream) {
    (void)in_sizes; (void)n_in; (void)d_ws; (void)ws_size; (void)out_size;
    const float* x    = (const float*)d_in[0];
    const float* eWih = (const float*)d_in[1];
    const float* eWhh = (const float*)d_in[2];
    const float* ebih = (const float*)d_in[3];
    const float* ebhh = (const float*)d_in[4];
    const float* dWih = (const float*)d_in[5];
    const float* dWhh = (const float*)d_in[6];
    const float* dbih = (const float*)d_in[7];
    const float* dbhh = (const float*)d_in[8];
    const float* linW = (const float*)d_in[9];
    const float* linb = (const float*)d_in[10];
    float* out = (float*)d_out;

    rae_gru_kernel<<<dim3(B_TOT / BT), dim3(512), 0, stream>>>(
        x, eWih, eWhh, ebih, ebhh, dWih, dWhh, dbih, dbhh, linW, linb, out);
}

// Round 4
// 291.277 us; speedup vs baseline: 1.4340x; 1.0213x over previous
//
#include <hip/hip_runtime.h>
#include <cstdint>

// GRU recurrent autoencoder, MI355X persistent-MFMA implementation, round 11.
// B=2048, T=128, X=38, H=128, 3H=384. fp32 I/O, fp16 MFMA operands,
// fp32 accumulation + fp32 recurrent state (in registers).
//
// Round 11 = round 10 (230us rocprof: MfmaUtil 28, VALUBusy 36, occ 23%) with
// the two biggest in-step wastes removed:
//  * Persistent C-init vectors: all accumulator inits (biases + zero) hoisted
//    to loop-invariant f32x4 registers used as the C operand of each chain's
//    first MFMA. Removes ~28 v_mov/wave/step (~110 cyc/SIMD/step of VALU).
//  * Encoder x-GEMM software pipeline: the 6 x-part MFMAs for step t+1 are
//    computed at the END of step t (xchunk is read-only within a chunk -> no
//    barrier needed). They fill the matrix pipe during the activation/write
//    phase, come off the critical path, and shorten the r/z h-chains to
//    2-deep (x result is the chain's C base). Ping-pong xg register sets
//    match the 2-step unrolled loop. Chunk seam: one zeroed pad t-slot makes
//    the final next-x read in-bounds; its (bias-only) result is discarded and
//    recomputed by XG_CALC at the next chunk head.
//  * xa1 read made unconditional (pad data zeroed; quads 1-3 hit zero
//    weights) -> no exec-mask divergence on the x reads.
// Kept from r10: BT=8/grid 256 (dup=2 forced optimum), x in LDS fp16
// [t][8][40], HS=136, 2-step unrolled ping-pong h buffers, balanced 2+2
// MFMA chains, __syncthreads everywhere, decoder algebra (r/z folded
// dWhh+dWih*linW, n-gate W2 separate, proj overlapped, t=0 pre-step).

#define T_SEQ 128
#define X_DIM 38
#define H_DIM 128
#define B_TOT 2048
#define BT    8
#define HS    136   // h row stride in halfs: 68 dw == 4 mod 32 -> 8-row spread
#define XK    40    // x row stride in halfs: 20 dw -> 8-row spread
#define XCH   64    // x chunk length (timesteps)

#define HB_BYTES   (2 * BT * HS * 2)             // 4352
#define XC_BYTES   ((XCH + 1) * BT * XK * 2)     // 41600 (pad slot; >= 32768 w2lds)
#define SMEM_BYTES (HB_BYTES + XC_BYTES)         // 45952

typedef _Float16 half8 __attribute__((ext_vector_type(8)));
typedef float    f32x4 __attribute__((ext_vector_type(4)));

#define MF(a, b, c) __builtin_amdgcn_mfma_f32_16x16x32_f16((a), (b), (c), 0, 0, 0)

__device__ __forceinline__ float fast_sigmoid(float x) {
    return __builtin_amdgcn_rcpf(1.0f + __expf(-x));
}
__device__ __forceinline__ float fast_tanh(float x) {
    return 1.0f - 2.0f * __builtin_amdgcn_rcpf(1.0f + __expf(2.0f * x));
}

// compute x-part accumulators (bias-seeded) for local timestep TLOC
#define XG_CALC(TLOC, OUTr, OUTz, OUTn)                                        \
    do {                                                                       \
        const _Float16* xr_ = xchunk + ((TLOC) * BT + arow) * XK;              \
        half8 x0_ = *(const half8*)(xr_ + quad * 8);                           \
        half8 x1_ = *(const half8*)(xr_ + 32);                                 \
        OUTr = MF(x0_, wxe[0][0], vb_r);                                       \
        OUTr = MF(x1_, wxe[0][1], OUTr);                                       \
        OUTz = MF(x0_, wxe[1][0], vb_z);                                       \
        OUTz = MF(x1_, wxe[1][1], OUTz);                                       \
        OUTn = MF(x0_, wxe[2][0], vb_ngi);                                     \
        OUTn = MF(x1_, wxe[2][1], OUTn);                                       \
    } while (0)

// one encoder step: h(t) from HRD, x-part for t in IN*, h(t+1) -> HWR,
// x-part for t+1 -> OUT* (filled into the act/write shadow).
#define ENC_STEP(HRD, HWR, TLOC, INr, INz, INn, OUTr, OUTz, OUTn)              \
    do {                                                                       \
        const _Float16* xn_ = xchunk + (((TLOC) + 1) * BT + arow) * XK;        \
        half8 xn0_ = *(const half8*)(xn_ + quad * 8);                          \
        half8 xn1_ = *(const half8*)(xn_ + 32);                                \
        const _Float16* hb_ = (HRD) + arow * HS + quad * 8;                    \
        half8 h0_ = *(const half8*)(hb_ + 0 * 32);                             \
        half8 h1_ = *(const half8*)(hb_ + 1 * 32);                             \
        half8 h2_ = *(const half8*)(hb_ + 2 * 32);                             \
        half8 h3_ = *(const half8*)(hb_ + 3 * 32);                             \
        f32x4 ar_ = MF(h0_, wh[0][0], INr);                                    \
        ar_ = MF(h1_, wh[0][1], ar_);                                          \
        f32x4 arB_ = MF(h2_, wh[0][2], vzero);                                 \
        arB_ = MF(h3_, wh[0][3], arB_);                                        \
        f32x4 az_ = MF(h0_, wh[1][0], INz);                                    \
        az_ = MF(h1_, wh[1][1], az_);                                          \
        f32x4 azB_ = MF(h2_, wh[1][2], vzero);                                 \
        azB_ = MF(h3_, wh[1][3], azB_);                                        \
        f32x4 gn_ = MF(h0_, wh[2][0], vb_ngh);                                 \
        gn_ = MF(h1_, wh[2][1], gn_);                                          \
        f32x4 gnB_ = MF(h2_, wh[2][2], vzero);                                 \
        gnB_ = MF(h3_, wh[2][3], gnB_);                                        \
        _Pragma("unroll")                                                      \
        for (int e_ = 0; e_ < 2; ++e_) {                                       \
            const int rg_ = 2 * e_;   /* valid C rows: reg 0 / reg 2 */        \
            const float r_ = fast_sigmoid(ar_[rg_] + arB_[rg_]);               \
            const float z_ = fast_sigmoid(az_[rg_] + azB_[rg_]);               \
            const float n_ = fast_tanh(INn[rg_] + r_ * (gn_[rg_] + gnB_[rg_]));\
            const float h_ = n_ + z_ * (hold[e_] - n_);                        \
            hold[e_] = h_;                                                     \
            (HWR)[(2 * quad + e_) * HS + j] = (_Float16)h_;                    \
        }                                                                      \
        OUTr = MF(xn0_, wxe[0][0], vb_r);       /* t+1 x-part: fills the */    \
        OUTr = MF(xn1_, wxe[0][1], OUTr);       /* act/write shadow      */    \
        OUTz = MF(xn0_, wxe[1][0], vb_z);                                      \
        OUTz = MF(xn1_, wxe[1][1], OUTz);                                      \
        OUTn = MF(xn0_, wxe[2][0], vb_ngi);                                    \
        OUTn = MF(xn1_, wxe[2][1], OUTn);                                      \
        __syncthreads();                                                       \
    } while (0)

// one decoder step: d(t) from HRD, d(t+1) -> HWR, o(TOUT) stored
#define DEC_STEP(HRD, HWR, TOUT)                                               \
    do {                                                                       \
        const _Float16* hb_ = (HRD) + arow * HS + quad * 8;                    \
        half8 h0_ = *(const half8*)(hb_ + 0 * 32);                             \
        half8 h1_ = *(const half8*)(hb_ + 1 * 32);                             \
        half8 h2_ = *(const half8*)(hb_ + 2 * 32);                             \
        half8 h3_ = *(const half8*)(hb_ + 3 * 32);                             \
        if (wv < 3) {   /* o_{TOUT} = d @ linW^T + lb, store early */          \
            f32x4 al_ = MF(h0_, wl[0], vb_lb);                                 \
            al_ = MF(h1_, wl[1], al_);                                         \
            f32x4 alB_ = MF(h2_, wl[2], vzero);                                \
            alB_ = MF(h3_, wl[3], alB_);                                       \
            if (nv) {                                                          \
                out[obase0 + (size_t)(TOUT) * X_DIM] = al_[0] + alB_[0];       \
                out[obase1 + (size_t)(TOUT) * X_DIM] = al_[2] + alB_[2];       \
            }                                                                  \
        }                                                                      \
        f32x4 ar_ = MF(h0_, wh[0][0], vd_r);                                   \
        ar_ = MF(h1_, wh[0][1], ar_);                                          \
        f32x4 arB_ = MF(h2_, wh[0][2], vzero);                                 \
        arB_ = MF(h3_, wh[0][3], arB_);                                        \
        f32x4 az_ = MF(h0_, wh[1][0], vd_z);                                   \
        az_ = MF(h1_, wh[1][1], az_);                                          \
        f32x4 azB_ = MF(h2_, wh[1][2], vzero);                                 \
        azB_ = MF(h3_, wh[1][3], azB_);                                        \
        f32x4 gn_ = MF(h0_, wh[2][0], vd_gh);                                  \
        gn_ = MF(h1_, wh[2][1], gn_);                                          \
        f32x4 gnB_ = MF(h2_, wh[2][2], vzero);                                 \
        gnB_ = MF(h3_, wh[2][3], gnB_);                                        \
        f32x4 gi_ = MF(h0_, wxn[0], vd_gi);                                    \
        gi_ = MF(h1_, wxn[1], gi_);                                            \
        f32x4 giB_ = MF(h2_, wxn[2], vzero);                                   \
        giB_ = MF(h3_, wxn[3], giB_);                                          \
        _Pragma("unroll")                                                      \
        for (int e_ = 0; e_ < 2; ++e_) {                                       \
            const int rg_ = 2 * e_;                                            \
            const float r_ = fast_sigmoid(ar_[rg_] + arB_[rg_]);               \
            const float z_ = fast_sigmoid(az_[rg_] + azB_[rg_]);               \
            const float n_ = fast_tanh((gi_[rg_] + giB_[rg_]) +                \
                                       r_ * (gn_[rg_] + gnB_[rg_]));           \
            const float h_ = n_ + z_ * (hold[e_] - n_);                        \
            hold[e_] = h_;                                                     \
            (HWR)[(2 * quad + e_) * HS + j] = (_Float16)h_;                    \
        }                                                                      \
        __syncthreads();                                                       \
    } while (0)

__global__ __launch_bounds__(512, 2)
void rae_gru_kernel(const float* __restrict__ x,
                    const float* __restrict__ eWih, const float* __restrict__ eWhh,
                    const float* __restrict__ ebih, const float* __restrict__ ebhh,
                    const float* __restrict__ dWih, const float* __restrict__ dWhh,
                    const float* __restrict__ dbih, const float* __restrict__ dbhh,
                    const float* __restrict__ linW, const float* __restrict__ linb,
                    float* __restrict__ out)
{
    __shared__ __align__(16) unsigned char smem[SMEM_BYTES];
    _Float16* const hbuf0  = (_Float16*)smem;                 // [BT][HS]
    _Float16* const hbuf1  = hbuf0 + BT * HS;                 // [BT][HS]
    _Float16* const xchunk = (_Float16*)(smem + HB_BYTES);    // [XCH+1][BT][XK]
    _Float16* const w2lds  = xchunk;                          // [128][128] alias (x dead)

    const int tid  = threadIdx.x;
    const int wv   = tid >> 6;        // 0..7
    const int ln   = tid & 63;
    const int quad = ln >> 4;         // A/B: k-group; C: row-group
    const int mrow = ln & 15;         // A: m-row / B,C: col-in-tile
    const int b0   = blockIdx.x * BT;
    const int arow = mrow >> 1;       // batch row this A-lane reads (b at m=2b)
    const int j    = wv * 16 + mrow;  // this lane's gate column (8 waves x 16)
    const int jc0  = j, jc1 = H_DIM + j, jc2 = 2 * H_DIM + j;

    {   // zero h buffers + whole x region (pad slot + pad cols stay 0)
        uint32_t* hz = (uint32_t*)smem;
        #pragma unroll 1
        for (int i = tid; i < SMEM_BYTES / 4; i += 512) hz[i] = 0u;
    }

    // ---- x chunk staging: 512 thr = 64 t x 8 rows, fp16 [t][row][XK] ----
    auto stage_x = [&](int tb) {
        const int st = tid & 63, sr = tid >> 6;
        const float* src = x + ((size_t)(b0 + sr) * T_SEQ + tb + st) * X_DIM;
        _Float16* dst = xchunk + ((size_t)st * BT + sr) * XK;
        float v[38];
        #pragma unroll
        for (int u = 0; u < 19; ++u) {
            float2 w = *(const float2*)(src + 2 * u);
            v[2 * u] = w.x; v[2 * u + 1] = w.y;
        }
        #pragma unroll
        for (int c = 0; c < 4; ++c) {
            half8 hv;
            #pragma unroll
            for (int e = 0; e < 8; ++e) hv[e] = (_Float16)v[c * 8 + e];
            *(half8*)(dst + c * 8) = hv;
        }
        {
            half8 hv;
            #pragma unroll
            for (int e = 0; e < 6; ++e) hv[e] = (_Float16)v[32 + e];
            hv[6] = (_Float16)0.0f; hv[7] = (_Float16)0.0f;
            *(half8*)(dst + 32) = hv;
        }
    };
    stage_x(0);

    // ---- persistent weight fragments (1 col-triple per wave) ----
    half8 wh[3][4];    // enc: eWhh | dec: r/z combined, n pure dWhh
    half8 wxe[3][2];   // encoder Wih (K padded 38->64); dead after encoder
    half8 wxn[4];      // decoder n-gate W2
    half8 wl[4];       // linear head
    const f32x4 vzero = { 0.f, 0.f, 0.f, 0.f };

    #pragma unroll
    for (int p = 0; p < 3; ++p) {
        const int jp = p * H_DIM + j;
        const float* wr = eWhh + (size_t)jp * H_DIM;
        #pragma unroll
        for (int c = 0; c < 4; ++c) {
            const int kb = c * 32 + quad * 8;
            half8 v;
            #pragma unroll
            for (int e = 0; e < 8; ++e) v[e] = (_Float16)wr[kb + e];
            wh[p][c] = v;
        }
        const float* wir = eWih + (size_t)jp * X_DIM;
        #pragma unroll
        for (int c = 0; c < 2; ++c) {
            const int kb = c * 32 + quad * 8;
            half8 v;
            #pragma unroll
            for (int e = 0; e < 8; ++e) {
                const int k = kb + e;
                v[e] = (k < X_DIM) ? (_Float16)wir[k] : (_Float16)0.0f;
            }
            wxe[p][c] = v;
        }
    }
    const float eb_r   = ebih[jc0] + ebhh[jc0];
    const float eb_z   = ebih[jc1] + ebhh[jc1];
    const float eb_ngi = ebih[jc2];
    const float eb_ngh = ebhh[jc2];
    const f32x4 vb_r   = { eb_r, eb_r, eb_r, eb_r };
    const f32x4 vb_z   = { eb_z, eb_z, eb_z, eb_z };
    const f32x4 vb_ngi = { eb_ngi, eb_ngi, eb_ngi, eb_ngi };
    const f32x4 vb_ngh = { eb_ngh, eb_ngh, eb_ngh, eb_ngh };

    float hold[2] = { 0.0f, 0.0f };   // h[2quad+e][j] in fp32

    __syncthreads();     // staging + zero complete

    // ================= encoder (2 chunks x 32 unrolled pairs) =============
    f32x4 xgAr, xgAz, xgAn, xgBr, xgBz, xgBn;
    #pragma unroll 1
    for (int ch = 0; ch < 2; ++ch) {
        XG_CALC(0, xgAr, xgAz, xgAn);
        #pragma unroll 1
        for (int i = 0; i < 32; ++i) {
            ENC_STEP(hbuf0, hbuf1, 2 * i,     xgAr, xgAz, xgAn, xgBr, xgBz, xgBn);
            ENC_STEP(hbuf1, hbuf0, 2 * i + 1, xgBr, xgBz, xgBn, xgAr, xgAz, xgAn);
        }
        // i=31 second step computed xgA from the zeroed pad slot -> junk,
        // discarded (recomputed at next chunk head / unused after chunk 2).
        if (ch == 0) {
            stage_x(XCH);
            __syncthreads();
        }
    }
    // h_enc now in hbuf0

    // ================= decoder weight prep =================
    // Step A: pure dWhh frags + biases.
    #pragma unroll
    for (int p = 0; p < 3; ++p) {
        const float* wr = dWhh + (size_t)(p * H_DIM + j) * H_DIM;
        #pragma unroll
        for (int c = 0; c < 4; ++c) {
            const int kb = c * 32 + quad * 8;
            half8 v;
            #pragma unroll
            for (int e = 0; e < 8; ++e) v[e] = (_Float16)wr[kb + e];
            wh[p][c] = v;
        }
    }
    const float c_r0 = dbih[jc0] + dbhh[jc0];
    const float c_z0 = dbih[jc1] + dbhh[jc1];
    const float c_n0 = dbih[jc2];
    const float d_ngh = dbhh[jc2];
    const f32x4 vd_gh = { d_ngh, d_ngh, d_ngh, d_ngh };

    // Step B: t=0 pre-step (gi = bias only). h_enc in hbuf0 -> d_1 to hbuf1.
    {
        const _Float16* hb_ = hbuf0 + arow * HS + quad * 8;
        half8 h0_ = *(const half8*)(hb_ + 0 * 32);
        half8 h1_ = *(const half8*)(hb_ + 1 * 32);
        half8 h2_ = *(const half8*)(hb_ + 2 * 32);
        half8 h3_ = *(const half8*)(hb_ + 3 * 32);
        f32x4 ar_ = { c_r0, c_r0, c_r0, c_r0 };
        ar_ = MF(h0_, wh[0][0], ar_);
        ar_ = MF(h1_, wh[0][1], ar_);
        f32x4 arB_ = MF(h2_, wh[0][2], vzero);
        arB_ = MF(h3_, wh[0][3], arB_);
        f32x4 az_ = { c_z0, c_z0, c_z0, c_z0 };
        az_ = MF(h0_, wh[1][0], az_);
        az_ = MF(h1_, wh[1][1], az_);
        f32x4 azB_ = MF(h2_, wh[1][2], vzero);
        azB_ = MF(h3_, wh[1][3], azB_);
        f32x4 gn_ = MF(h0_, wh[2][0], vd_gh);
        gn_ = MF(h1_, wh[2][1], gn_);
        f32x4 gnB_ = MF(h2_, wh[2][2], vzero);
        gnB_ = MF(h3_, wh[2][3], gnB_);
        #pragma unroll
        for (int e_ = 0; e_ < 2; ++e_) {
            const int rg_ = 2 * e_;
            const float r_ = fast_sigmoid(ar_[rg_] + arB_[rg_]);
            const float z_ = fast_sigmoid(az_[rg_] + azB_[rg_]);
            const float n_ = fast_tanh(c_n0 + r_ * (gn_[rg_] + gnB_[rg_]));
            const float h_ = n_ + z_ * (hold[e_] - n_);
            hold[e_] = h_;
            hbuf1[(2 * quad + e_) * HS + j] = (_Float16)h_;
        }
    }
    __syncthreads();

    // Step C: fold W2 = dWih*linW. r/z: wh <- fp16(dWhh + W2); n: wxn <- fp16(W2).
    // (w2lds aliases xchunk; x is dead.)
    {
        const int kk = ((wv & 1) << 6) | ln;      // 0..127, lane's W2 column
        const int jb = (wv >> 1) * 32;            // 4 wave-pairs x 32 rows = 128
        float lc[X_DIM];
        #pragma unroll
        for (int m = 0; m < X_DIM; ++m) lc[m] = linW[m * H_DIM + kk];

        // gate 0 (r): combined
        #pragma unroll 1
        for (int jj = 0; jj < 32; ++jj) {
            const int jr = __builtin_amdgcn_readfirstlane(jb + jj);
            const float* dwr = dWih + (size_t)jr * X_DIM;
            float sacc = dWhh[(size_t)jr * H_DIM + kk];
            #pragma unroll
            for (int m = 0; m < X_DIM; ++m) sacc += dwr[m] * lc[m];
            w2lds[jr * H_DIM + kk] = (_Float16)sacc;
        }
        __syncthreads();
        #pragma unroll
        for (int c = 0; c < 4; ++c)
            wh[0][c] = *(const half8*)&w2lds[j * H_DIM + c * 32 + quad * 8];
        __syncthreads();

        // gate 1 (z): combined
        #pragma unroll 1
        for (int jj = 0; jj < 32; ++jj) {
            const int jr = __builtin_amdgcn_readfirstlane(jb + jj);
            const float* dwr = dWih + (size_t)(H_DIM + jr) * X_DIM;
            float sacc = dWhh[(size_t)(H_DIM + jr) * H_DIM + kk];
            #pragma unroll
            for (int m = 0; m < X_DIM; ++m) sacc += dwr[m] * lc[m];
            w2lds[jr * H_DIM + kk] = (_Float16)sacc;
        }
        __syncthreads();
        #pragma unroll
        for (int c = 0; c < 4; ++c)
            wh[1][c] = *(const half8*)&w2lds[j * H_DIM + c * 32 + quad * 8];
        __syncthreads();

        // gate 2 (n): W2 only (wh[2] stays pure dWhh)
        #pragma unroll 1
        for (int jj = 0; jj < 32; ++jj) {
            const int jr = __builtin_amdgcn_readfirstlane(jb + jj);
            const float* dwr = dWih + (size_t)(2 * H_DIM + jr) * X_DIM;
            float sacc = 0.0f;
            #pragma unroll
            for (int m = 0; m < X_DIM; ++m) sacc += dwr[m] * lc[m];
            w2lds[jr * H_DIM + kk] = (_Float16)sacc;
        }
        __syncthreads();
        #pragma unroll
        for (int c = 0; c < 4; ++c)
            wxn[c] = *(const half8*)&w2lds[j * H_DIM + c * 32 + quad * 8];
        __syncthreads();
    }

    // Step D: linear head frags + folded biases for t>=1.
    const int nlin = wv * 16 + mrow;          // waves 0..2 cover cols 0..47
    const bool nv = (wv < 3) && (nlin < X_DIM);
    float lb = 0.0f;
    {
        const float* lr = linW + (size_t)(nv ? nlin : 0) * H_DIM;
        #pragma unroll
        for (int c = 0; c < 4; ++c) {
            const int kb = c * 32 + quad * 8;
            half8 v;
            #pragma unroll
            for (int e = 0; e < 8; ++e)
                v[e] = nv ? (_Float16)lr[kb + e] : (_Float16)0.0f;
            wl[c] = v;
        }
        if (nv) lb = linb[nlin];
    }
    float db_r, db_z, db_gi;
    {
        float bf[3];
        #pragma unroll
        for (int p = 0; p < 3; ++p) {
            const float* dwr = dWih + (size_t)(p * H_DIM + j) * X_DIM;
            float sacc = 0.0f;
            #pragma unroll
            for (int m = 0; m < X_DIM; ++m) sacc += linb[m] * dwr[m];
            bf[p] = sacc;
        }
        db_r  = c_r0 + bf[0];
        db_z  = c_z0 + bf[1];
        db_gi = c_n0 + bf[2];
    }
    const f32x4 vd_r  = { db_r, db_r, db_r, db_r };
    const f32x4 vd_z  = { db_z, db_z, db_z, db_z };
    const f32x4 vd_gi = { db_gi, db_gi, db_gi, db_gi };
    const f32x4 vb_lb = { lb, lb, lb, lb };

    const size_t obase0 = ((size_t)(b0 + 2 * quad)     * T_SEQ) * X_DIM + nlin;
    const size_t obase1 = ((size_t)(b0 + 2 * quad + 1) * T_SEQ) * X_DIM + nlin;

    // ================= decoder (t=1..127, 63 unrolled pairs + tail) ========
    #pragma unroll 1
    for (int i = 0; i < 63; ++i) {
        DEC_STEP(hbuf1, hbuf0, 2 * i);        // t = 2i+1, stores o_{2i}
        DEC_STEP(hbuf0, hbuf1, 2 * i + 1);    // t = 2i+2, stores o_{2i+1}
    }
    DEC_STEP(hbuf1, hbuf0, 126);              // t = 127, stores o_126; d_128 -> hbuf0

    // tail projection: o_127 = d_128 @ linW^T + lb (d_128 in hbuf0)
    if (wv < 3) {
        const _Float16* hb_ = hbuf0 + arow * HS + quad * 8;
        half8 h0_ = *(const half8*)(hb_ + 0 * 32);
        half8 h1_ = *(const half8*)(hb_ + 1 * 32);
        half8 h2_ = *(const half8*)(hb_ + 2 * 32);
        half8 h3_ = *(const half8*)(hb_ + 3 * 32);
        f32x4 al_ = MF(h0_, wl[0], vb_lb);
        al_ = MF(h1_, wl[1], al_);
        f32x4 alB_ = MF(h2_, wl[2], vzero);
        alB_ = MF(h3_, wl[3], alB_);
        if (nv) {
            out[obase0 + (size_t)(T_SEQ - 1) * X_DIM] = al_[0] + alB_[0];
            out[obase1 + (size_t)(T_SEQ - 1) * X_DIM] = al_[2] + alB_[2];
        }
    }
}

extern "C" void kernel_launch(void* const* d_in, const int* in_sizes, int n_in,
                              void* d_out, int out_size, void* d_ws, size_t ws_size,
                              hipStream_t stream) {
    (void)in_sizes; (void)n_in; (void)d_ws; (void)ws_size; (void)out_size;
    const float* x    = (const float*)d_in[0];
    const float* eWih = (const float*)d_in[1];
    const float* eWhh = (const float*)d_in[2];
    const float* ebih = (const float*)d_in[3];
    const float* ebhh = (const float*)d_in[4];
    const float* dWih = (const float*)d_in[5];
    const float* dWhh = (const float*)d_in[6];
    const float* dbih = (const float*)d_in[7];
    const float* dbhh = (const float*)d_in[8];
    const float* linW = (const float*)d_in[9];
    const float* linb = (const float*)d_in[10];
    float* out = (float*)d_out;

    rae_gru_kernel<<<dim3(B_TOT / BT), dim3(512), 0, stream>>>(
        x, eWih, eWhh, ebih, ebhh, dWih, dWhh, dbih, dbhh, linW, linb, out);
}